// Round 12
// baseline (263.312 us; speedup 1.0000x reference)
//
#include <hip/hip_runtime.h>
#include <hip/hip_bf16.h>
#include <math.h>

typedef unsigned short bf16u;
typedef __attribute__((ext_vector_type(8))) short short8;
typedef __attribute__((ext_vector_type(4))) float floatx4;

__device__ __forceinline__ float bf2f(bf16u u) {
  union { unsigned int i; float f; } c;
  c.i = ((unsigned int)u) << 16;
  return c.f;
}
__device__ __forceinline__ bf16u f2bf(float f) {
  union { float f; unsigned int i; } c;
  c.f = f;
  unsigned int lsb = (c.i >> 16) & 1u;
  c.i += 0x7fffu + lsb;
  return (bf16u)(c.i >> 16);
}

__device__ __forceinline__ void load_lds16(const void* g, void* l) {
  __builtin_amdgcn_global_load_lds(
      (const __attribute__((address_space(1))) void*)g,
      (__attribute__((address_space(3))) void*)l, 16, 0, 0);
}

// ---------------------------------------------------------------- LayerNorm row
__device__ __forceinline__ void ln_row(
    const float* __restrict__ xr, bf16u* __restrict__ orow,
    const float* __restrict__ gamma, const float* __restrict__ beta,
    float* red, int tid) {
  const int lane = tid & 63, wave = tid >> 6;
  float4 v = ((const float4*)xr)[tid];
  float s = v.x + v.y + v.z + v.w;
#pragma unroll
  for (int off = 32; off; off >>= 1) s += __shfl_down(s, off);
  if (lane == 0) red[wave] = s;
  __syncthreads();
  const float mean = (red[0] + red[1] + red[2] + red[3]) * (1.0f / 1024.0f);
  __syncthreads();
  float d0 = v.x - mean, d1 = v.y - mean, d2 = v.z - mean, d3 = v.w - mean;
  float sq = d0 * d0 + d1 * d1 + d2 * d2 + d3 * d3;
#pragma unroll
  for (int off = 32; off; off >>= 1) sq += __shfl_down(sq, off);
  if (lane == 0) red[wave] = sq;
  __syncthreads();
  const float var = (red[0] + red[1] + red[2] + red[3]) * (1.0f / 1023.0f);
  const float inv = 1.0f / (sqrtf(var) + 1e-8f);
  float4 g = ((const float4*)gamma)[tid];
  float4 b = ((const float4*)beta)[tid];
  uint2 pk;
  pk.x = (unsigned int)f2bf(d0 * inv * g.x + b.x) |
         ((unsigned int)f2bf(d1 * inv * g.y + b.y) << 16);
  pk.y = (unsigned int)f2bf(d2 * inv * g.z + b.z) |
         ((unsigned int)f2bf(d3 * inv * g.w + b.w) << 16);
  *(uint2*)(orow + tid * 4) = pk;
}

__global__ __launch_bounds__(256) void ln_kernel(
    const float* __restrict__ x, bf16u* __restrict__ out,
    const float* __restrict__ gamma, const float* __restrict__ beta) {
  __shared__ float red[4];
  const int row = blockIdx.x;
  ln_row(x + (size_t)row * 1024, out + (size_t)row * 1024, gamma, beta, red,
         threadIdx.x);
}

// ---------------------------------------------------------------- Weight pack + LN1
// Merged: pack (blocks 0..12287) and LN1 (blocks 12288..14335) co-schedule.
// Widened transpose stores (uint2 = 4 bf16 / lane).
__global__ __launch_bounds__(256) void pack_ln(
    const float* __restrict__ wq, const float* __restrict__ wk,
    const float* __restrict__ wv, const float* __restrict__ wo,
    const float* __restrict__ w1, const float* __restrict__ w2,
    bf16u* __restrict__ WqkvT, bf16u* __restrict__ woT,
    bf16u* __restrict__ w1T, bf16u* __restrict__ w2T,
    const float* __restrict__ x, bf16u* __restrict__ hln,
    const float* __restrict__ g1, const float* __restrict__ be1) {
  __shared__ bf16u tile[32][33];
  __shared__ float red[4];
  const int id = blockIdx.x;
  if (id >= 12288) {
    const int row = id - 12288;
    ln_row(x + (size_t)row * 1024, hln + (size_t)row * 1024, g1, be1, red,
           threadIdx.x);
    return;
  }
  const float* in; bf16u* out; int R, C, bx, by;
  if (id < 3072) {            // wq/wk/wv: 16 heads x (1024 x 64)
    int job = id >> 10, rem = id & 1023;
    int head = rem >> 6, t = rem & 63;
    bx = t & 1; by = t >> 1;
    in = (job == 0 ? wq : (job == 1 ? wk : wv)) + head * 65536;
    out = WqkvT + job * 1048576 + head * 65536;
    R = 1024; C = 64;
  } else if (id < 4096) {     // wo: 1024 x 1024
    int rem = id - 3072; bx = rem & 31; by = rem >> 5;
    in = wo; out = woT; R = 1024; C = 1024;
  } else if (id < 8192) {     // w1: 1024 x 4096
    int rem = id - 4096; bx = rem & 127; by = rem >> 7;
    in = w1; out = w1T; R = 1024; C = 4096;
  } else {                    // w2: 4096 x 1024
    int rem = id - 8192; bx = rem & 31; by = rem >> 5;
    in = w2; out = w2T; R = 4096; C = 1024;
  }
  const int bc = bx * 32, br = by * 32;
  {
    const int row = threadIdx.x >> 3, c4 = (threadIdx.x & 7) * 4;
    float4 v = *(const float4*)(in + (size_t)(br + row) * C + bc + c4);
    tile[row][c4 + 0] = f2bf(v.x);
    tile[row][c4 + 1] = f2bf(v.y);
    tile[row][c4 + 2] = f2bf(v.z);
    tile[row][c4 + 3] = f2bf(v.w);
  }
  __syncthreads();
  // out[(bc+oc)*R + br + orow] = tile[orow][oc]; pack 4 consecutive orow.
  const int oc = threadIdx.x >> 3, g4 = (threadIdx.x & 7) * 4;
  uint2 pk;
  pk.x = (unsigned int)tile[g4 + 0][oc] | ((unsigned int)tile[g4 + 1][oc] << 16);
  pk.y = (unsigned int)tile[g4 + 2][oc] | ((unsigned int)tile[g4 + 3][oc] << 16);
  *(uint2*)(out + (size_t)(bc + oc) * R + br + g4) = pk;
}

// ---------------------------------------------------------------- GEMM (B^T)
// Single-buffer, 16KB LDS. T1 bijective XCD-chunked block swizzle: each XCD
// gets a CONTIGUOUS tile chunk so its 4MB L2 holds a slice of one operand
// plus the whole other. LINY=1 chunks B-columns (weight-heavy GEMMs),
// LINY=0 chunks A-rows. (Round-11 lesson: this helps GEMMs whose panels
// exceed L2; it REGRESSED flash_attn whose K/V was already cache-hit.)
template <int BM, int BN, int WGR, int WGC, int EPI, int MINW = 4, int LINY = 0>
__global__ __launch_bounds__(256, MINW) void gemm_bt(
    const bf16u* __restrict__ A, const bf16u* __restrict__ Bt,
    const float* __restrict__ bias, const float* __restrict__ res,
    void* __restrict__ Cout, int M, int N, int K, int kchunk) {
  constexpr int BK = 64;
  constexpr int TM = BM / WGR, TN = BN / WGC;
  constexpr int NI = TM / 16, NJ = TN / 16;
  alignas(16) __shared__ bf16u sA[BM * BK];
  alignas(16) __shared__ bf16u sB[BN * BK];
  const int tid = threadIdx.x, lane = tid & 63, wave = tid >> 6;
  const int wr = wave / WGC, wc = wave % WGC;
  const int quad = lane >> 4, l16 = lane & 15;
  // ---- XCD-chunked bijective swizzle: hw dispatch id -> tile id
  const int nwg = (int)(gridDim.x * gridDim.y);
  const int hw = (int)(blockIdx.y * gridDim.x + blockIdx.x);
  const int tile = (hw & 7) * (nwg >> 3) + (hw >> 3);
  int bx, by;
  if constexpr (LINY) { bx = tile / (int)gridDim.y; by = tile % (int)gridDim.y; }
  else                { by = tile / (int)gridDim.x; bx = tile % (int)gridDim.x; }
  const int m0 = by * BM, n0 = bx * BN;
  const int kz = blockIdx.z;
  const int kbeg = kz * kchunk;
  const int kend = (kbeg + kchunk < K) ? (kbeg + kchunk) : K;

  floatx4 acc[NI][NJ] = {};
  constexpr int ACH = BM * BK / 8;
  constexpr int BCH = BN * BK / 8;

  for (int k0 = kbeg; k0 < kend; k0 += BK) {
#pragma unroll
    for (int c = tid; c < ACH; c += 256) {
      int r = c >> 3, kc = ((c ^ r) & 7) * 8;  // swizzled source chunk
      load_lds16(A + (size_t)(m0 + r) * K + k0 + kc, (void*)(sA + c * 8));
    }
#pragma unroll
    for (int c = tid; c < BCH; c += 256) {
      int r = c >> 3, kc = ((c ^ r) & 7) * 8;
      load_lds16(Bt + (size_t)(n0 + r) * K + k0 + kc, (void*)(sB + c * 8));
    }
    __syncthreads();
#pragma unroll
    for (int kk = 0; kk < BK; kk += 32) {
      const int ch = (kk >> 3) + quad;
      short8 af[NI], bf[NJ];
#pragma unroll
      for (int i = 0; i < NI; i++) {
        const int R = wr * TM + i * 16 + l16;
        af[i] = *(const short8*)(sA + R * BK + ((ch ^ (R & 7)) << 3));
      }
#pragma unroll
      for (int j = 0; j < NJ; j++) {
        const int R = wc * TN + j * 16 + l16;
        bf[j] = *(const short8*)(sB + R * BK + ((ch ^ (R & 7)) << 3));
      }
#pragma unroll
      for (int i = 0; i < NI; i++)
#pragma unroll
        for (int j = 0; j < NJ; j++)
          acc[i][j] = __builtin_amdgcn_mfma_f32_16x16x32_bf16(af[i], bf[j], acc[i][j], 0, 0, 0);
    }
    __syncthreads();
  }

  float* pout = (float*)Cout;
  if constexpr (EPI == 3) pout += (size_t)kz * M * N;
#pragma unroll
  for (int j = 0; j < NJ; j++) {
    const int col = n0 + wc * TN + j * 16 + l16;
    float bv = 0.0f;
    if constexpr (EPI == 1 || EPI == 2) bv = bias[col];
#pragma unroll
    for (int i = 0; i < NI; i++) {
      if constexpr (EPI == 4) {
        const int row0 = m0 + wr * TM + i * 16 + quad * 4;
        if (col < 2048) {
#pragma unroll
          for (int r = 0; r < 4; r++)
            ((bf16u*)Cout)[(size_t)(row0 + r) * N + col] = f2bf(acc[i][j][r]);
        } else {
          // V fragment: 4 consecutive rows, same col -> one packed store
          // into Vtr[col-2048][row0..row0+3].
          uint2 pk;
          pk.x = (unsigned int)f2bf(acc[i][j][0]) |
                 ((unsigned int)f2bf(acc[i][j][1]) << 16);
          pk.y = (unsigned int)f2bf(acc[i][j][2]) |
                 ((unsigned int)f2bf(acc[i][j][3]) << 16);
          *(uint2*)((bf16u*)res + (size_t)(col - 2048) * 2048 + row0) = pk;
        }
      } else {
#pragma unroll
        for (int r = 0; r < 4; r++) {
          const int row = m0 + wr * TM + i * 16 + quad * 4 + r;
          const size_t o = (size_t)row * N + col;
          const float v = acc[i][j][r];
          if constexpr (EPI == 0) {
            ((bf16u*)Cout)[o] = f2bf(v);
          } else if constexpr (EPI == 1) {
            pout[o] = v + bv + res[o];
          } else if constexpr (EPI == 2) {
            float t = v + bv;
            ((bf16u*)Cout)[o] = f2bf(0.5f * t * (1.0f + erff(t * 0.70710678118654752f)));
          } else if constexpr (EPI == 3) {
            pout[o] = v;
          }
        }
      }
    }
  }
}

// ---------------------------------------------------------------- split-K reduce (FFN2)
__global__ __launch_bounds__(256) void reduce2_kernel(
    const float* __restrict__ part, const float* __restrict__ bias,
    const float* __restrict__ res, float* __restrict__ out,
    int N, size_t total) {
  size_t i = ((size_t)blockIdx.x * 256 + threadIdx.x) * 4;
  if (i >= total) return;
  float4 a = *(const float4*)(part + i);
  float4 b = *(const float4*)(part + total + i);
  float4 r = *(const float4*)(res + i);
  float4 bv = *(const float4*)(bias + (int)(i & (size_t)(N - 1)));
  float4 o;
  o.x = a.x + b.x + r.x + bv.x;
  o.y = a.y + b.y + r.y + bv.y;
  o.z = a.z + b.z + r.z + bv.z;
  o.w = a.w + b.w + r.w + bv.w;
  *(float4*)(out + i) = o;
}

// ---------------------------------------------------------------- Flash attention v3
// 64-wide K tiles, dedicated sP, global_load_lds staging with pre-swizzled
// source, 2-barrier/tile pipeline. T5 setprio around MFMA clusters.
// Round-12: plain block mapping (round-11's XCD swizzle regressed — K/V
// was already cache-hit, FETCH=8MB); NZ=4 for load-balance granularity
// (Occ 21% at NZ=2: 1024 blocks = 4/CU under the 5/CU cap, 0-16 iters
// per block; NZ=4 gives 2048 blocks, 8/CU queued, max 8 iters).
template <int NZ>
__global__ __launch_bounds__(256, 5) void flash_attn(
    const bf16u* __restrict__ QKV, const bf16u* __restrict__ Vt,
    bf16u* __restrict__ partO, float* __restrict__ partL) {
  const int qb = 31 - blockIdx.x;   // heavy q-blocks launch first
  const int h = blockIdx.y;
  const int z = blockIdx.z;
  const int tid = threadIdx.x, lane = tid & 63, wave = tid >> 6;
  const int quad = lane >> 4, l16 = lane & 15;
  alignas(16) __shared__ bf16u sQ[64 * 64];   // 8 KB
  alignas(16) __shared__ bf16u sK[64 * 64];   // 8 KB
  alignas(16) __shared__ bf16u sVt[64 * 64];  // 8 KB
  alignas(16) __shared__ bf16u sP[64 * 64];   // 8 KB, dedicated (no overlay)
  const int q0 = qb * 64;
  const int nkt = qb + 1;          // 64-wide K tiles
  const int rq = wave * 16 + l16;

#pragma unroll
  for (int c = tid; c < 512; c += 256) {
    int r = c >> 3, kc = (c ^ r) & 7;
    load_lds16(QKV + (size_t)(q0 + r) * 3072 + h * 64 + kc * 8, (void*)(sQ + c * 8));
  }
  int kt = z;
  if (kt < nkt) {
    const int c0 = kt * 64;
#pragma unroll
    for (int c = tid; c < 512; c += 256) {
      int r = c >> 3, kc = (c ^ r) & 7;
      load_lds16(QKV + (size_t)(c0 + r) * 3072 + 1024 + h * 64 + kc * 8, (void*)(sK + c * 8));
    }
#pragma unroll
    for (int c = tid; c < 512; c += 256) {
      int e = c >> 3, kc = (c ^ e) & 7;
      load_lds16(Vt + (size_t)(h * 64 + e) * 2048 + c0 + kc * 8, (void*)(sVt + c * 8));
    }
  }
  __syncthreads();

  floatx4 acc_l = {0.f, 0.f, 0.f, 0.f};
  floatx4 aco[4] = {};
  short8 ones;
#pragma unroll
  for (int u = 0; u < 8; u++) ones[u] = (short)0x3F80;  // bf16 1.0

  for (; kt < nkt; kt += NZ) {
    const int c0 = kt * 64;
    // ---- QK^T (swapped operands: C col = q index, lane-local k along rows)
    floatx4 s[4] = {};
    __builtin_amdgcn_s_setprio(1);
#pragma unroll
    for (int kk = 0; kk < 64; kk += 32) {
      const int ch = (kk >> 3) + quad;
      short8 aq = *(const short8*)(sQ + rq * 64 + ((ch ^ (rq & 7)) << 3));
#pragma unroll
      for (int nt = 0; nt < 4; nt++) {
        const int rk = nt * 16 + l16;
        short8 bk = *(const short8*)(sK + rk * 64 + ((ch ^ (rk & 7)) << 3));
        s[nt] = __builtin_amdgcn_mfma_f32_16x16x32_bf16(bk, aq, s[nt], 0, 0, 0);
      }
    }
    __builtin_amdgcn_s_setprio(0);
    // ---- fixed-max softmax numerator (values bounded; no running max)
    const float C = 0.125f * 1.44269504088896f;  // 1/sqrt(64) * log2(e)
    const bool diag = (kt == qb);                // only diagonal tile masks
#pragma unroll
    for (int nt = 0; nt < 4; nt++)
#pragma unroll
      for (int r = 0; r < 4; r++) {
        float t = s[nt][r] * C;
        if (diag) {
          const int kpos = c0 + nt * 16 + quad * 4 + r;
          if (kpos > q0 + rq) t = -__builtin_inff();
        }
        s[nt][r] = __builtin_amdgcn_exp2f(t);
      }
    // ---- pack P rows into dedicated sP (per-wave-exclusive: no barrier)
#pragma unroll
    for (int nt = 0; nt < 4; nt++) {
      unsigned int lo = (unsigned int)f2bf(s[nt][0]) | ((unsigned int)f2bf(s[nt][1]) << 16);
      unsigned int hi = (unsigned int)f2bf(s[nt][2]) | ((unsigned int)f2bf(s[nt][3]) << 16);
      uint2 pk; pk.x = lo; pk.y = hi;
      const int e0 = nt * 16 + quad * 4;
      const int cch = e0 >> 3, sub = e0 & 7;
      *(uint2*)(sP + rq * 64 + ((cch ^ (rq & 7)) << 3) + sub) = pk;
    }
    __syncthreads();  // barrier 1: sK reads done; drains last V prefetch
    if (kt + NZ < nkt) {   // K prefetch hides under PV
      const int c0n = (kt + NZ) * 64;
#pragma unroll
      for (int c = tid; c < 512; c += 256) {
        int r = c >> 3, kc = (c ^ r) & 7;
        load_lds16(QKV + (size_t)(c0n + r) * 3072 + 1024 + h * 64 + kc * 8,
                   (void*)(sK + c * 8));
      }
    }
    // ---- PV + row-sum (ones column)
    __builtin_amdgcn_s_setprio(1);
#pragma unroll
    for (int kk = 0; kk < 64; kk += 32) {
      const int ch = (kk >> 3) + quad;
      short8 ap = *(const short8*)(sP + rq * 64 + ((ch ^ (rq & 7)) << 3));
#pragma unroll
      for (int dt = 0; dt < 4; dt++) {
        const int rv = dt * 16 + l16;
        short8 bv = *(const short8*)(sVt + rv * 64 + ((ch ^ (rv & 7)) << 3));
        aco[dt] = __builtin_amdgcn_mfma_f32_16x16x32_bf16(ap, bv, aco[dt], 0, 0, 0);
      }
      acc_l = __builtin_amdgcn_mfma_f32_16x16x32_bf16(ap, ones, acc_l, 0, 0, 0);
    }
    __builtin_amdgcn_s_setprio(0);
    __syncthreads();  // barrier 2: drains K prefetch; sVt reads done
    if (kt + NZ < nkt) {   // V prefetch hides under next QK^T + softmax
      const int c0n = (kt + NZ) * 64;
#pragma unroll
      for (int c = tid; c < 512; c += 256) {
        int e = c >> 3, kc = (c ^ e) & 7;
        load_lds16(Vt + (size_t)(h * 64 + e) * 2048 + c0n + kc * 8,
                   (void*)(sVt + c * 8));
      }
    }
  }

  // write partials (zero-iteration blocks write zeros — every slot covered once)
  bf16u* po = partO + ((size_t)z * 2048 + q0) * 1024 + h * 64;
#pragma unroll
  for (int dt = 0; dt < 4; dt++)
#pragma unroll
    for (int r = 0; r < 4; r++)
      po[(wave * 16 + quad * 4 + r) * 1024 + dt * 16 + l16] = f2bf(aco[dt][r]);
  if (l16 == 0) {
#pragma unroll
    for (int r = 0; r < 4; r++)
      partL[((size_t)z * 2048 + q0 + wave * 16 + quad * 4 + r) * 16 + h] = acc_l[r];
  }
}

// combine: ctx[t][col] = sum_z O_z / sum_z l_z
template <int NZ>
__global__ __launch_bounds__(256) void attn_reduce(
    const bf16u* __restrict__ partO, const float* __restrict__ partL,
    bf16u* __restrict__ ctx) {
  const int t = blockIdx.x;
  const int col = threadIdx.x * 4;
  const int h = col >> 6;
  float l = 0.f;
#pragma unroll
  for (int z = 0; z < NZ; z++) l += partL[((size_t)z * 2048 + t) * 16 + h];
  float o0 = 0.f, o1 = 0.f, o2 = 0.f, o3 = 0.f;
#pragma unroll
  for (int z = 0; z < NZ; z++) {
    uint2 v = *(const uint2*)(partO + ((size_t)z * 2048 + t) * 1024 + col);
    o0 += bf2f((bf16u)(v.x & 0xffff)); o1 += bf2f((bf16u)(v.x >> 16));
    o2 += bf2f((bf16u)(v.y & 0xffff)); o3 += bf2f((bf16u)(v.y >> 16));
  }
  const float inv = 1.0f / l;
  uint2 pk;
  pk.x = (unsigned int)f2bf(o0 * inv) | ((unsigned int)f2bf(o1 * inv) << 16);
  pk.y = (unsigned int)f2bf(o2 * inv) | ((unsigned int)f2bf(o3 * inv) << 16);
  *(uint2*)(ctx + (size_t)t * 1024 + col) = pk;
}

// ---------------------------------------------------------------- launch
extern "C" void kernel_launch(void* const* d_in, const int* in_sizes, int n_in,
                              void* d_out, int out_size, void* d_ws, size_t ws_size,
                              hipStream_t stream) {
  (void)in_sizes; (void)n_in; (void)out_size; (void)ws_size;
  const float* x   = (const float*)d_in[0];
  const float* wq  = (const float*)d_in[1];
  const float* wk  = (const float*)d_in[2];
  const float* wv  = (const float*)d_in[3];
  const float* wo  = (const float*)d_in[4];
  const float* bo  = (const float*)d_in[5];
  const float* g1  = (const float*)d_in[6];
  const float* be1 = (const float*)d_in[7];
  const float* g2  = (const float*)d_in[8];
  const float* be2 = (const float*)d_in[9];
  const float* w1  = (const float*)d_in[10];
  const float* bb1 = (const float*)d_in[11];
  const float* w2  = (const float*)d_in[12];
  const float* bb2 = (const float*)d_in[13];

  char* p = (char*)d_ws;
  const size_t MB = 1024 * 1024;
  constexpr int NZ = 4;
  bf16u* WqkvT = (bf16u*)(p + 0 * MB);
  bf16u* woT   = (bf16u*)(p + 6 * MB);
  bf16u* w1T   = (bf16u*)(p + 8 * MB);
  bf16u* w2T   = (bf16u*)(p + 16 * MB);
  bf16u* multi = (bf16u*)(p + 24 * MB);   // hln -> ctx -> h2 (sequentially dead)
  bf16u* QKV   = (bf16u*)(p + 28 * MB);   // 12 MB (V cols unwritten/unused)
  float* partL = (float*)(p + 40 * MB);   // 512 KB (NZ=4)
  bf16u* partO = (bf16u*)(p + 41 * MB);   // 16 MB (NZ=4)
  float* x1    = (float*)(p + 57 * MB);   // 8 MB
  bf16u* Vtr   = (bf16u*)(p + 65 * MB);   // 4 MB (own space: written while hln live)
  bf16u* mid   = (bf16u*)(p + 28 * MB);   // reuse QKV region for FFN mid
  float* partF = (float*)(p + 0 * MB);    // overlays packed weights (dead by FFN2)
  bf16u* hln = multi, *ctx = multi, *h2 = multi;

  // pack weights + LN1 (independent; one launch, co-scheduled)
  pack_ln<<<14336, 256, 0, stream>>>(wq, wk, wv, wo, w1, w2,
                                     WqkvT, woT, w1T, w2T, x, hln, g1, be1);
  // QKV = h @ [wq|wk|wv]; V third written transposed straight to Vtr (EPI=4)
  // LINY=1: chunk B-cols per XCD (B=6MB > A=4MB)
  gemm_bt<64, 64, 2, 2, 4, 6, 1><<<dim3(48, 32, 1), 256, 0, stream>>>(
      hln, WqkvT, nullptr, (const float*)Vtr, QKV, 2048, 3072, 1024, 1024);
  // split-K flash attention (2048 blocks, plain mapping, NZ=4) + combine
  flash_attn<NZ><<<dim3(32, 16, NZ), 256, 0, stream>>>(QKV, Vtr, partO, partL);
  attn_reduce<NZ><<<2048, 256, 0, stream>>>(partO, partL, ctx);
  // x1 = x + ctx @ wo + bo (fp32) — LINY=0: chunk A-rows (A=4MB > B=2MB)
  gemm_bt<32, 64, 2, 2, 1, 6, 0><<<dim3(16, 64, 1), 256, 0, stream>>>(
      ctx, woT, bo, x, x1, 2048, 1024, 1024, 1024);
  // h2 = LN2(x1); mid = gelu(h2 @ w1 + b1) — LINY=1: chunk B-cols (B=8MB)
  ln_kernel<<<2048, 256, 0, stream>>>(x1, h2, g2, be2);
  gemm_bt<64, 64, 2, 2, 2, 6, 1><<<dim3(64, 32, 1), 256, 0, stream>>>(
      h2, w1T, bb1, nullptr, mid, 2048, 4096, 1024, 1024);
  // out = x1 + mid @ w2 + b2 : split-K=2 + fused reduce
  // LINY=0: chunk A-rows (A=mid 8MB/kz > B=4MB/kz)
  gemm_bt<64, 64, 2, 2, 3, 6, 0><<<dim3(16, 32, 2), 256, 0, stream>>>(
      mid, w2T, nullptr, nullptr, partF, 2048, 1024, 4096, 2048);
  reduce2_kernel<<<2048, 256, 0, stream>>>(partF, bb2, x1, (float*)d_out,
                                           1024, (size_t)2048 * 1024);
}

// Round 13
// 244.964 us; speedup vs baseline: 1.0749x; 1.0749x over previous
//
#include <hip/hip_runtime.h>
#include <hip/hip_bf16.h>
#include <math.h>

typedef unsigned short bf16u;
typedef __attribute__((ext_vector_type(8))) short short8;
typedef __attribute__((ext_vector_type(4))) float floatx4;

__device__ __forceinline__ float bf2f(bf16u u) {
  union { unsigned int i; float f; } c;
  c.i = ((unsigned int)u) << 16;
  return c.f;
}
__device__ __forceinline__ bf16u f2bf(float f) {
  union { float f; unsigned int i; } c;
  c.f = f;
  unsigned int lsb = (c.i >> 16) & 1u;
  c.i += 0x7fffu + lsb;
  return (bf16u)(c.i >> 16);
}

__device__ __forceinline__ void load_lds16(const void* g, void* l) {
  __builtin_amdgcn_global_load_lds(
      (const __attribute__((address_space(1))) void*)g,
      (__attribute__((address_space(3))) void*)l, 16, 0, 0);
}

// ---------------------------------------------------------------- LayerNorm row
__device__ __forceinline__ void ln_row(
    const float* __restrict__ xr, bf16u* __restrict__ orow,
    const float* __restrict__ gamma, const float* __restrict__ beta,
    float* red, int tid) {
  const int lane = tid & 63, wave = tid >> 6;
  float4 v = ((const float4*)xr)[tid];
  float s = v.x + v.y + v.z + v.w;
#pragma unroll
  for (int off = 32; off; off >>= 1) s += __shfl_down(s, off);
  if (lane == 0) red[wave] = s;
  __syncthreads();
  const float mean = (red[0] + red[1] + red[2] + red[3]) * (1.0f / 1024.0f);
  __syncthreads();
  float d0 = v.x - mean, d1 = v.y - mean, d2 = v.z - mean, d3 = v.w - mean;
  float sq = d0 * d0 + d1 * d1 + d2 * d2 + d3 * d3;
#pragma unroll
  for (int off = 32; off; off >>= 1) sq += __shfl_down(sq, off);
  if (lane == 0) red[wave] = sq;
  __syncthreads();
  const float var = (red[0] + red[1] + red[2] + red[3]) * (1.0f / 1023.0f);
  const float inv = 1.0f / (sqrtf(var) + 1e-8f);
  float4 g = ((const float4*)gamma)[tid];
  float4 b = ((const float4*)beta)[tid];
  uint2 pk;
  pk.x = (unsigned int)f2bf(d0 * inv * g.x + b.x) |
         ((unsigned int)f2bf(d1 * inv * g.y + b.y) << 16);
  pk.y = (unsigned int)f2bf(d2 * inv * g.z + b.z) |
         ((unsigned int)f2bf(d3 * inv * g.w + b.w) << 16);
  *(uint2*)(orow + tid * 4) = pk;
}

__global__ __launch_bounds__(256) void ln_kernel(
    const float* __restrict__ x, bf16u* __restrict__ out,
    const float* __restrict__ gamma, const float* __restrict__ beta) {
  __shared__ float red[4];
  const int row = blockIdx.x;
  ln_row(x + (size_t)row * 1024, out + (size_t)row * 1024, gamma, beta, red,
         threadIdx.x);
}

// ---------------------------------------------------------------- Weight pack + LN1
// Merged: pack (blocks 0..12287) and LN1 (blocks 12288..14335) co-schedule.
// Widened transpose stores (uint2 = 4 bf16 / lane).
__global__ __launch_bounds__(256) void pack_ln(
    const float* __restrict__ wq, const float* __restrict__ wk,
    const float* __restrict__ wv, const float* __restrict__ wo,
    const float* __restrict__ w1, const float* __restrict__ w2,
    bf16u* __restrict__ WqkvT, bf16u* __restrict__ woT,
    bf16u* __restrict__ w1T, bf16u* __restrict__ w2T,
    const float* __restrict__ x, bf16u* __restrict__ hln,
    const float* __restrict__ g1, const float* __restrict__ be1) {
  __shared__ bf16u tile[32][33];
  __shared__ float red[4];
  const int id = blockIdx.x;
  if (id >= 12288) {
    const int row = id - 12288;
    ln_row(x + (size_t)row * 1024, hln + (size_t)row * 1024, g1, be1, red,
           threadIdx.x);
    return;
  }
  const float* in; bf16u* out; int R, C, bx, by;
  if (id < 3072) {            // wq/wk/wv: 16 heads x (1024 x 64)
    int job = id >> 10, rem = id & 1023;
    int head = rem >> 6, t = rem & 63;
    bx = t & 1; by = t >> 1;
    in = (job == 0 ? wq : (job == 1 ? wk : wv)) + head * 65536;
    out = WqkvT + job * 1048576 + head * 65536;
    R = 1024; C = 64;
  } else if (id < 4096) {     // wo: 1024 x 1024
    int rem = id - 3072; bx = rem & 31; by = rem >> 5;
    in = wo; out = woT; R = 1024; C = 1024;
  } else if (id < 8192) {     // w1: 1024 x 4096
    int rem = id - 4096; bx = rem & 127; by = rem >> 7;
    in = w1; out = w1T; R = 1024; C = 4096;
  } else {                    // w2: 4096 x 1024
    int rem = id - 8192; bx = rem & 31; by = rem >> 5;
    in = w2; out = w2T; R = 4096; C = 1024;
  }
  const int bc = bx * 32, br = by * 32;
  {
    const int row = threadIdx.x >> 3, c4 = (threadIdx.x & 7) * 4;
    float4 v = *(const float4*)(in + (size_t)(br + row) * C + bc + c4);
    tile[row][c4 + 0] = f2bf(v.x);
    tile[row][c4 + 1] = f2bf(v.y);
    tile[row][c4 + 2] = f2bf(v.z);
    tile[row][c4 + 3] = f2bf(v.w);
  }
  __syncthreads();
  // out[(bc+oc)*R + br + orow] = tile[orow][oc]; pack 4 consecutive orow.
  const int oc = threadIdx.x >> 3, g4 = (threadIdx.x & 7) * 4;
  uint2 pk;
  pk.x = (unsigned int)tile[g4 + 0][oc] | ((unsigned int)tile[g4 + 1][oc] << 16);
  pk.y = (unsigned int)tile[g4 + 2][oc] | ((unsigned int)tile[g4 + 3][oc] << 16);
  *(uint2*)(out + (size_t)(bc + oc) * R + br + g4) = pk;
}

// ---------------------------------------------------------------- GEMM (B^T)
// Single-buffer, 16KB LDS. T1 bijective XCD-chunked block swizzle: each XCD
// gets a CONTIGUOUS tile chunk so its 4MB L2 holds a slice of one operand
// plus the whole other. LINY=1 chunks B-columns (weight-heavy GEMMs),
// LINY=0 chunks A-rows.
template <int BM, int BN, int WGR, int WGC, int EPI, int MINW = 4, int LINY = 0>
__global__ __launch_bounds__(256, MINW) void gemm_bt(
    const bf16u* __restrict__ A, const bf16u* __restrict__ Bt,
    const float* __restrict__ bias, const float* __restrict__ res,
    void* __restrict__ Cout, int M, int N, int K, int kchunk) {
  constexpr int BK = 64;
  constexpr int TM = BM / WGR, TN = BN / WGC;
  constexpr int NI = TM / 16, NJ = TN / 16;
  alignas(16) __shared__ bf16u sA[BM * BK];
  alignas(16) __shared__ bf16u sB[BN * BK];
  const int tid = threadIdx.x, lane = tid & 63, wave = tid >> 6;
  const int wr = wave / WGC, wc = wave % WGC;
  const int quad = lane >> 4, l16 = lane & 15;
  // ---- XCD-chunked bijective swizzle: hw dispatch id -> tile id
  const int nwg = (int)(gridDim.x * gridDim.y);
  const int hw = (int)(blockIdx.y * gridDim.x + blockIdx.x);
  const int tile = (hw & 7) * (nwg >> 3) + (hw >> 3);
  int bx, by;
  if constexpr (LINY) { bx = tile / (int)gridDim.y; by = tile % (int)gridDim.y; }
  else                { by = tile / (int)gridDim.x; bx = tile % (int)gridDim.x; }
  const int m0 = by * BM, n0 = bx * BN;
  const int kz = blockIdx.z;
  const int kbeg = kz * kchunk;
  const int kend = (kbeg + kchunk < K) ? (kbeg + kchunk) : K;

  floatx4 acc[NI][NJ] = {};
  constexpr int ACH = BM * BK / 8;
  constexpr int BCH = BN * BK / 8;

  for (int k0 = kbeg; k0 < kend; k0 += BK) {
#pragma unroll
    for (int c = tid; c < ACH; c += 256) {
      int r = c >> 3, kc = ((c ^ r) & 7) * 8;  // swizzled source chunk
      load_lds16(A + (size_t)(m0 + r) * K + k0 + kc, (void*)(sA + c * 8));
    }
#pragma unroll
    for (int c = tid; c < BCH; c += 256) {
      int r = c >> 3, kc = ((c ^ r) & 7) * 8;
      load_lds16(Bt + (size_t)(n0 + r) * K + k0 + kc, (void*)(sB + c * 8));
    }
    __syncthreads();
#pragma unroll
    for (int kk = 0; kk < BK; kk += 32) {
      const int ch = (kk >> 3) + quad;
      short8 af[NI], bf[NJ];
#pragma unroll
      for (int i = 0; i < NI; i++) {
        const int R = wr * TM + i * 16 + l16;
        af[i] = *(const short8*)(sA + R * BK + ((ch ^ (R & 7)) << 3));
      }
#pragma unroll
      for (int j = 0; j < NJ; j++) {
        const int R = wc * TN + j * 16 + l16;
        bf[j] = *(const short8*)(sB + R * BK + ((ch ^ (R & 7)) << 3));
      }
#pragma unroll
      for (int i = 0; i < NI; i++)
#pragma unroll
        for (int j = 0; j < NJ; j++)
          acc[i][j] = __builtin_amdgcn_mfma_f32_16x16x32_bf16(af[i], bf[j], acc[i][j], 0, 0, 0);
    }
    __syncthreads();
  }

  float* pout = (float*)Cout;
  if constexpr (EPI == 3) pout += (size_t)kz * M * N;
#pragma unroll
  for (int j = 0; j < NJ; j++) {
    const int col = n0 + wc * TN + j * 16 + l16;
    float bv = 0.0f;
    if constexpr (EPI == 1 || EPI == 2) bv = bias[col];
#pragma unroll
    for (int i = 0; i < NI; i++) {
      if constexpr (EPI == 4) {
        const int row0 = m0 + wr * TM + i * 16 + quad * 4;
        if (col < 2048) {
#pragma unroll
          for (int r = 0; r < 4; r++)
            ((bf16u*)Cout)[(size_t)(row0 + r) * N + col] = f2bf(acc[i][j][r]);
        } else {
          // V fragment: 4 consecutive rows, same col -> one packed store
          // into Vtr[col-2048][row0..row0+3].
          uint2 pk;
          pk.x = (unsigned int)f2bf(acc[i][j][0]) |
                 ((unsigned int)f2bf(acc[i][j][1]) << 16);
          pk.y = (unsigned int)f2bf(acc[i][j][2]) |
                 ((unsigned int)f2bf(acc[i][j][3]) << 16);
          *(uint2*)((bf16u*)res + (size_t)(col - 2048) * 2048 + row0) = pk;
        }
      } else {
#pragma unroll
        for (int r = 0; r < 4; r++) {
          const int row = m0 + wr * TM + i * 16 + quad * 4 + r;
          const size_t o = (size_t)row * N + col;
          const float v = acc[i][j][r];
          if constexpr (EPI == 0) {
            ((bf16u*)Cout)[o] = f2bf(v);
          } else if constexpr (EPI == 1) {
            pout[o] = v + bv + res[o];
          } else if constexpr (EPI == 2) {
            float t = v + bv;
            ((bf16u*)Cout)[o] = f2bf(0.5f * t * (1.0f + erff(t * 0.70710678118654752f)));
          } else if constexpr (EPI == 3) {
            pout[o] = v;
          }
        }
      }
    }
  }
}

// ---------------------------------------------------------------- split-K reduce (FFN2)
__global__ __launch_bounds__(256) void reduce2_kernel(
    const float* __restrict__ part, const float* __restrict__ bias,
    const float* __restrict__ res, float* __restrict__ out,
    int N, size_t total) {
  size_t i = ((size_t)blockIdx.x * 256 + threadIdx.x) * 4;
  if (i >= total) return;
  float4 a = *(const float4*)(part + i);
  float4 b = *(const float4*)(part + total + i);
  float4 r = *(const float4*)(res + i);
  float4 bv = *(const float4*)(bias + (int)(i & (size_t)(N - 1)));
  float4 o;
  o.x = a.x + b.x + r.x + bv.x;
  o.y = a.y + b.y + r.y + bv.y;
  o.z = a.z + b.z + r.z + bv.z;
  o.w = a.w + b.w + r.w + bv.w;
  *(float4*)(out + i) = o;
}

// ---------------------------------------------------------------- Flash attention v3
// 64-wide K tiles, dedicated sP, global_load_lds staging with pre-swizzled
// source, 2-barrier/tile pipeline. T5 setprio around MFMA clusters.
// Round-13: CU-complementary qb mapping. With NZ=2 all 1024 blocks are
// co-resident (4/CU) and CU ~ id mod 256, so a CU's 4 blocks are
// (x,h,z*),(x,h+8,z*) — the old qb=31-x gave every CU a SINGLE qb (work
// 2..64 tile-iters, Occ 21%). Making qb h-dependent pairs complementary
// loads: per-CU work = (32-x)+(x+1) = 33 for all x.
template <int NZ>
__global__ __launch_bounds__(256, 5) void flash_attn(
    const bf16u* __restrict__ QKV, const bf16u* __restrict__ Vt,
    bf16u* __restrict__ partO, float* __restrict__ partL) {
  const int h = blockIdx.y;
  const int qb = (h < 8) ? (31 - (int)blockIdx.x) : (int)blockIdx.x;
  const int z = blockIdx.z;
  const int tid = threadIdx.x, lane = tid & 63, wave = tid >> 6;
  const int quad = lane >> 4, l16 = lane & 15;
  alignas(16) __shared__ bf16u sQ[64 * 64];   // 8 KB
  alignas(16) __shared__ bf16u sK[64 * 64];   // 8 KB
  alignas(16) __shared__ bf16u sVt[64 * 64];  // 8 KB
  alignas(16) __shared__ bf16u sP[64 * 64];   // 8 KB, dedicated (no overlay)
  const int q0 = qb * 64;
  const int nkt = qb + 1;          // 64-wide K tiles
  const int rq = wave * 16 + l16;

#pragma unroll
  for (int c = tid; c < 512; c += 256) {
    int r = c >> 3, kc = (c ^ r) & 7;
    load_lds16(QKV + (size_t)(q0 + r) * 3072 + h * 64 + kc * 8, (void*)(sQ + c * 8));
  }
  int kt = z;
  if (kt < nkt) {
    const int c0 = kt * 64;
#pragma unroll
    for (int c = tid; c < 512; c += 256) {
      int r = c >> 3, kc = (c ^ r) & 7;
      load_lds16(QKV + (size_t)(c0 + r) * 3072 + 1024 + h * 64 + kc * 8, (void*)(sK + c * 8));
    }
#pragma unroll
    for (int c = tid; c < 512; c += 256) {
      int e = c >> 3, kc = (c ^ e) & 7;
      load_lds16(Vt + (size_t)(h * 64 + e) * 2048 + c0 + kc * 8, (void*)(sVt + c * 8));
    }
  }
  __syncthreads();

  floatx4 acc_l = {0.f, 0.f, 0.f, 0.f};
  floatx4 aco[4] = {};
  short8 ones;
#pragma unroll
  for (int u = 0; u < 8; u++) ones[u] = (short)0x3F80;  // bf16 1.0

  for (; kt < nkt; kt += NZ) {
    const int c0 = kt * 64;
    // ---- QK^T (swapped operands: C col = q index, lane-local k along rows)
    floatx4 s[4] = {};
    __builtin_amdgcn_s_setprio(1);
#pragma unroll
    for (int kk = 0; kk < 64; kk += 32) {
      const int ch = (kk >> 3) + quad;
      short8 aq = *(const short8*)(sQ + rq * 64 + ((ch ^ (rq & 7)) << 3));
#pragma unroll
      for (int nt = 0; nt < 4; nt++) {
        const int rk = nt * 16 + l16;
        short8 bk = *(const short8*)(sK + rk * 64 + ((ch ^ (rk & 7)) << 3));
        s[nt] = __builtin_amdgcn_mfma_f32_16x16x32_bf16(bk, aq, s[nt], 0, 0, 0);
      }
    }
    __builtin_amdgcn_s_setprio(0);
    // ---- fixed-max softmax numerator (values bounded; no running max)
    const float C = 0.125f * 1.44269504088896f;  // 1/sqrt(64) * log2(e)
    const bool diag = (kt == qb);                // only diagonal tile masks
#pragma unroll
    for (int nt = 0; nt < 4; nt++)
#pragma unroll
      for (int r = 0; r < 4; r++) {
        float t = s[nt][r] * C;
        if (diag) {
          const int kpos = c0 + nt * 16 + quad * 4 + r;
          if (kpos > q0 + rq) t = -__builtin_inff();
        }
        s[nt][r] = __builtin_amdgcn_exp2f(t);
      }
    // ---- pack P rows into dedicated sP (per-wave-exclusive: no barrier)
#pragma unroll
    for (int nt = 0; nt < 4; nt++) {
      unsigned int lo = (unsigned int)f2bf(s[nt][0]) | ((unsigned int)f2bf(s[nt][1]) << 16);
      unsigned int hi = (unsigned int)f2bf(s[nt][2]) | ((unsigned int)f2bf(s[nt][3]) << 16);
      uint2 pk; pk.x = lo; pk.y = hi;
      const int e0 = nt * 16 + quad * 4;
      const int cch = e0 >> 3, sub = e0 & 7;
      *(uint2*)(sP + rq * 64 + ((cch ^ (rq & 7)) << 3) + sub) = pk;
    }
    __syncthreads();  // barrier 1: sK reads done; drains last V prefetch
    if (kt + NZ < nkt) {   // K prefetch hides under PV
      const int c0n = (kt + NZ) * 64;
#pragma unroll
      for (int c = tid; c < 512; c += 256) {
        int r = c >> 3, kc = (c ^ r) & 7;
        load_lds16(QKV + (size_t)(c0n + r) * 3072 + 1024 + h * 64 + kc * 8,
                   (void*)(sK + c * 8));
      }
    }
    // ---- PV + row-sum (ones column)
    __builtin_amdgcn_s_setprio(1);
#pragma unroll
    for (int kk = 0; kk < 64; kk += 32) {
      const int ch = (kk >> 3) + quad;
      short8 ap = *(const short8*)(sP + rq * 64 + ((ch ^ (rq & 7)) << 3));
#pragma unroll
      for (int dt = 0; dt < 4; dt++) {
        const int rv = dt * 16 + l16;
        short8 bv = *(const short8*)(sVt + rv * 64 + ((ch ^ (rv & 7)) << 3));
        aco[dt] = __builtin_amdgcn_mfma_f32_16x16x32_bf16(ap, bv, aco[dt], 0, 0, 0);
      }
      acc_l = __builtin_amdgcn_mfma_f32_16x16x32_bf16(ap, ones, acc_l, 0, 0, 0);
    }
    __builtin_amdgcn_s_setprio(0);
    __syncthreads();  // barrier 2: drains K prefetch; sVt reads done
    if (kt + NZ < nkt) {   // V prefetch hides under next QK^T + softmax
      const int c0n = (kt + NZ) * 64;
#pragma unroll
      for (int c = tid; c < 512; c += 256) {
        int e = c >> 3, kc = (c ^ e) & 7;
        load_lds16(Vt + (size_t)(h * 64 + e) * 2048 + c0n + kc * 8,
                   (void*)(sVt + c * 8));
      }
    }
  }

  // write partials (zero-iteration blocks write zeros — every slot covered once)
  bf16u* po = partO + ((size_t)z * 2048 + q0) * 1024 + h * 64;
#pragma unroll
  for (int dt = 0; dt < 4; dt++)
#pragma unroll
    for (int r = 0; r < 4; r++)
      po[(wave * 16 + quad * 4 + r) * 1024 + dt * 16 + l16] = f2bf(aco[dt][r]);
  if (l16 == 0) {
#pragma unroll
    for (int r = 0; r < 4; r++)
      partL[((size_t)z * 2048 + q0 + wave * 16 + quad * 4 + r) * 16 + h] = acc_l[r];
  }
}

// combine: ctx[t][col] = sum_z O_z / sum_z l_z
template <int NZ>
__global__ __launch_bounds__(256) void attn_reduce(
    const bf16u* __restrict__ partO, const float* __restrict__ partL,
    bf16u* __restrict__ ctx) {
  const int t = blockIdx.x;
  const int col = threadIdx.x * 4;
  const int h = col >> 6;
  float l = 0.f;
#pragma unroll
  for (int z = 0; z < NZ; z++) l += partL[((size_t)z * 2048 + t) * 16 + h];
  float o0 = 0.f, o1 = 0.f, o2 = 0.f, o3 = 0.f;
#pragma unroll
  for (int z = 0; z < NZ; z++) {
    uint2 v = *(const uint2*)(partO + ((size_t)z * 2048 + t) * 1024 + col);
    o0 += bf2f((bf16u)(v.x & 0xffff)); o1 += bf2f((bf16u)(v.x >> 16));
    o2 += bf2f((bf16u)(v.y & 0xffff)); o3 += bf2f((bf16u)(v.y >> 16));
  }
  const float inv = 1.0f / l;
  uint2 pk;
  pk.x = (unsigned int)f2bf(o0 * inv) | ((unsigned int)f2bf(o1 * inv) << 16);
  pk.y = (unsigned int)f2bf(o2 * inv) | ((unsigned int)f2bf(o3 * inv) << 16);
  *(uint2*)(ctx + (size_t)t * 1024 + col) = pk;
}

// ---------------------------------------------------------------- launch
extern "C" void kernel_launch(void* const* d_in, const int* in_sizes, int n_in,
                              void* d_out, int out_size, void* d_ws, size_t ws_size,
                              hipStream_t stream) {
  (void)in_sizes; (void)n_in; (void)out_size; (void)ws_size;
  const float* x   = (const float*)d_in[0];
  const float* wq  = (const float*)d_in[1];
  const float* wk  = (const float*)d_in[2];
  const float* wv  = (const float*)d_in[3];
  const float* wo  = (const float*)d_in[4];
  const float* bo  = (const float*)d_in[5];
  const float* g1  = (const float*)d_in[6];
  const float* be1 = (const float*)d_in[7];
  const float* g2  = (const float*)d_in[8];
  const float* be2 = (const float*)d_in[9];
  const float* w1  = (const float*)d_in[10];
  const float* bb1 = (const float*)d_in[11];
  const float* w2  = (const float*)d_in[12];
  const float* bb2 = (const float*)d_in[13];

  char* p = (char*)d_ws;
  const size_t MB = 1024 * 1024;
  constexpr int NZ = 2;
  bf16u* WqkvT = (bf16u*)(p + 0 * MB);
  bf16u* woT   = (bf16u*)(p + 6 * MB);
  bf16u* w1T   = (bf16u*)(p + 8 * MB);
  bf16u* w2T   = (bf16u*)(p + 16 * MB);
  bf16u* multi = (bf16u*)(p + 24 * MB);   // hln -> ctx -> h2 (sequentially dead)
  bf16u* QKV   = (bf16u*)(p + 28 * MB);   // 12 MB (V cols unwritten/unused)
  float* partL = (float*)(p + 40 * MB);   // 256 KB (NZ=2)
  bf16u* partO = (bf16u*)(p + 41 * MB);   // 8 MB (NZ=2)
  float* x1    = (float*)(p + 57 * MB);   // 8 MB
  bf16u* Vtr   = (bf16u*)(p + 65 * MB);   // 4 MB (own space: written while hln live)
  bf16u* mid   = (bf16u*)(p + 28 * MB);   // reuse QKV region for FFN mid
  float* partF = (float*)(p + 0 * MB);    // overlays packed weights (dead by FFN2)
  bf16u* hln = multi, *ctx = multi, *h2 = multi;

  // pack weights + LN1 (independent; one launch, co-scheduled)
  pack_ln<<<14336, 256, 0, stream>>>(wq, wk, wv, wo, w1, w2,
                                     WqkvT, woT, w1T, w2T, x, hln, g1, be1);
  // QKV = h @ [wq|wk|wv]; V third written transposed straight to Vtr (EPI=4)
  // LINY=1: chunk B-cols per XCD (B=6MB > A=4MB)
  gemm_bt<64, 64, 2, 2, 4, 6, 1><<<dim3(48, 32, 1), 256, 0, stream>>>(
      hln, WqkvT, nullptr, (const float*)Vtr, QKV, 2048, 3072, 1024, 1024);
  // split-K flash attention (1024 blocks, CU-complementary qb) + combine
  flash_attn<NZ><<<dim3(32, 16, NZ), 256, 0, stream>>>(QKV, Vtr, partO, partL);
  attn_reduce<NZ><<<2048, 256, 0, stream>>>(partO, partL, ctx);
  // x1 = x + ctx @ wo + bo (fp32) — LINY=0: chunk A-rows (A=4MB > B=2MB)
  gemm_bt<32, 64, 2, 2, 1, 6, 0><<<dim3(16, 64, 1), 256, 0, stream>>>(
      ctx, woT, bo, x, x1, 2048, 1024, 1024, 1024);
  // h2 = LN2(x1); mid = gelu(h2 @ w1 + b1) — LINY=1: chunk B-cols (B=8MB)
  ln_kernel<<<2048, 256, 0, stream>>>(x1, h2, g2, be2);
  gemm_bt<64, 64, 2, 2, 2, 6, 1><<<dim3(64, 32, 1), 256, 0, stream>>>(
      h2, w1T, bb1, nullptr, mid, 2048, 4096, 1024, 1024);
  // out = x1 + mid @ w2 + b2 : split-K=2 + fused reduce
  // LINY=0: chunk A-rows (A=mid 8MB/kz > B=4MB/kz)
  gemm_bt<64, 64, 2, 2, 3, 6, 0><<<dim3(16, 32, 2), 256, 0, stream>>>(
      mid, w2T, nullptr, nullptr, partF, 2048, 1024, 4096, 2048);
  reduce2_kernel<<<2048, 256, 0, stream>>>(partF, bb2, x1, (float*)d_out,
                                           1024, (size_t)2048 * 1024);
}